// Round 1
// baseline (1121.812 us; speedup 1.0000x reference)
//
#include <hip/hip_runtime.h>
#include <hip/hip_bf16.h>
#include <stdint.h>

// ---------------------------------------------------------------------------
// TransformerGNN: two TransformerConv layers (4 heads cat -> relu -> 1 head)
// N=50000 nodes, E=800000 edges, IN=128, HID*HEADS=128, OUT=64
// ---------------------------------------------------------------------------

__device__ __forceinline__ float b2f(uint16_t u) {
    union { uint32_t i; float f; } x; x.i = ((uint32_t)u) << 16; return x.f;
}
__device__ __forceinline__ uint16_t f2b(float f) {
    __hip_bfloat16 h = __float2bfloat16(f);
    union { __hip_bfloat16 h; uint16_t u; } c; c.h = h; return c.u;
}

// ---- pack 4 weight matrices (fp32) into one concat bf16 [K][4*Cper] + bias ----
__global__ void pack_weights(const float* __restrict__ Wq, const float* __restrict__ bq,
                             const float* __restrict__ Wk, const float* __restrict__ bk,
                             const float* __restrict__ Wv, const float* __restrict__ bv,
                             const float* __restrict__ Ws, const float* __restrict__ bs,
                             uint16_t* __restrict__ Wc, float* __restrict__ bc,
                             int K, int Cper)
{
    int Ntot = 4 * Cper;
    int idx = blockIdx.x * 256 + threadIdx.x;
    int total = K * Ntot;
    if (idx < total) {
        int k = idx / Ntot, col = idx % Ntot;
        int m = col / Cper, c = col % Cper;
        const float* Wm = (m == 0) ? Wq : (m == 1) ? Wk : (m == 2) ? Wv : Ws;
        Wc[idx] = f2b(Wm[k * Cper + c]);
    } else if (idx < total + Ntot) {
        int col = idx - total;
        int m = col / Cper, c = col % Cper;
        const float* bm = (m == 0) ? bq : (m == 1) ? bk : (m == 2) ? bv : bs;
        bc[col] = bm[c];
    }
}

// ---- fused GEMM: Y[M][Ntot] (bf16) = A[M][128] @ Wb[128][Ntot] + bias ----
// A is fp32 (layer 1: x) or bf16 (layer 2: h). Tile 64x64, K=128, 256 thr.
template <bool ABF16>
__global__ __launch_bounds__(256) void gemm_fused(
    const void* __restrict__ Aptr, const uint16_t* __restrict__ Wb,
    const float* __restrict__ bias, uint16_t* __restrict__ Y,
    int M, int Ntot)
{
    __shared__ float    Alds[64][132];   // +4 pad: conflict-free, 16B-aligned rows
    __shared__ uint16_t Wlds[128][64];

    const int tid = threadIdx.x;
    const int m0 = blockIdx.x * 64;
    const int n0 = blockIdx.y * 64;

    // stage A tile (64 rows x 128 cols)
    #pragma unroll
    for (int i = 0; i < 8; ++i) {
        int idx = tid + i * 256;             // 2048 granules of 4 floats
        int r = idx >> 5, c4 = (idx & 31) << 2;
        int gr = m0 + r;
        float4 v = make_float4(0.f, 0.f, 0.f, 0.f);
        if (gr < M) {
            if (!ABF16) {
                v = *reinterpret_cast<const float4*>((const float*)Aptr + (size_t)gr * 128 + c4);
            } else {
                ushort4 u = *reinterpret_cast<const ushort4*>((const uint16_t*)Aptr + (size_t)gr * 128 + c4);
                v = make_float4(b2f(u.x), b2f(u.y), b2f(u.z), b2f(u.w));
            }
        }
        *reinterpret_cast<float4*>(&Alds[r][c4]) = v;
    }
    // stage W tile (128 rows x 64 cols, bf16)
    #pragma unroll
    for (int i = 0; i < 8; ++i) {
        int idx = tid + i * 256;             // 2048 granules of 4 bf16
        int r = idx >> 4, c4 = (idx & 15) << 2;
        *reinterpret_cast<ushort4*>(&Wlds[r][c4]) =
            *reinterpret_cast<const ushort4*>(Wb + (size_t)r * Ntot + n0 + c4);
    }
    __syncthreads();

    const int ty = tid >> 4, tx = tid & 15;  // thread -> 4 rows x 4 cols
    float acc[4][4] = {};

    #pragma unroll 2
    for (int kk4 = 0; kk4 < 32; ++kk4) {
        float areg[4][4];
        #pragma unroll
        for (int i = 0; i < 4; ++i)
            *reinterpret_cast<float4*>(areg[i]) =
                *reinterpret_cast<const float4*>(&Alds[ty * 4 + i][kk4 * 4]);
        #pragma unroll
        for (int t = 0; t < 4; ++t) {
            int kk = kk4 * 4 + t;
            ushort4 wu = *reinterpret_cast<const ushort4*>(&Wlds[kk][tx * 4]);
            float w[4] = { b2f(wu.x), b2f(wu.y), b2f(wu.z), b2f(wu.w) };
            #pragma unroll
            for (int i = 0; i < 4; ++i)
                #pragma unroll
                for (int j = 0; j < 4; ++j)
                    acc[i][j] = fmaf(areg[i][t], w[j], acc[i][j]);
        }
    }

    #pragma unroll
    for (int i = 0; i < 4; ++i) {
        int gr = m0 + ty * 4 + i;
        if (gr < M) {
            uint16_t outv[4];
            #pragma unroll
            for (int j = 0; j < 4; ++j)
                outv[j] = f2b(acc[i][j] + bias[n0 + tx * 4 + j]);
            *reinterpret_cast<ushort4*>(Y + (size_t)gr * Ntot + n0 + tx * 4) =
                *reinterpret_cast<ushort4*>(outv);
        }
    }
}

// ---- edge pass, layer 1: 4 heads x 32 ch. One wave per edge. ----
// qkvs layout per node row of 512 bf16: [q 0:128 | k 128:256 | v 256:384 | s 384:512]
__global__ __launch_bounds__(256) void edge_pass1(
    const int* __restrict__ ei, int E,
    const uint16_t* __restrict__ qkvs,
    float* __restrict__ msg,        // [N][128] fp32 accum
    float* __restrict__ denom)      // [N][4]
{
    int e = (blockIdx.x * 256 + threadIdx.x) >> 6;
    if (e >= E) return;
    int lane = threadIdx.x & 63;
    int src = ei[e];
    int dst = ei[E + e];
    const uint16_t* qrow = qkvs + (size_t)dst * 512;
    const uint16_t* krow = qkvs + (size_t)src * 512 + 128;
    const uint16_t* vrow = qkvs + (size_t)src * 512 + 256;

    uint32_t qw = *reinterpret_cast<const uint32_t*>(qrow + 2 * lane);
    uint32_t kw = *reinterpret_cast<const uint32_t*>(krow + 2 * lane);
    float p = b2f((uint16_t)qw) * b2f((uint16_t)kw)
            + b2f((uint16_t)(qw >> 16)) * b2f((uint16_t)(kw >> 16));
    // reduce 32-channel dot within each 16-lane group (one head per group)
    p += __shfl_xor(p, 1);
    p += __shfl_xor(p, 2);
    p += __shfl_xor(p, 4);
    p += __shfl_xor(p, 8);
    float a = __expf(p * 0.17677669529663687f);   // 1/sqrt(32)
    if ((lane & 15) == 0)
        atomicAdd(&denom[(size_t)dst * 4 + (lane >> 4)], a);
    uint32_t vw = *reinterpret_cast<const uint32_t*>(vrow + 2 * lane);
    atomicAdd(&msg[(size_t)dst * 128 + 2 * lane],     a * b2f((uint16_t)vw));
    atomicAdd(&msg[(size_t)dst * 128 + 2 * lane + 1], a * b2f((uint16_t)(vw >> 16)));
}

// ---- finalize layer 1: h = relu(msg/denom + skip), bf16 ----
__global__ __launch_bounds__(256) void finalize1(
    const float* __restrict__ msg, const float* __restrict__ denom,
    const uint16_t* __restrict__ qkvs, uint16_t* __restrict__ h, int N)
{
    int idx = blockIdx.x * 256 + threadIdx.x;
    if (idx >= N * 128) return;
    int n = idx >> 7, c = idx & 127;
    float d = denom[n * 4 + (c >> 5)];
    float inv = (d > 0.f) ? 1.f / d : 0.f;
    float val = msg[idx] * inv + b2f(qkvs[(size_t)n * 512 + 384 + c]);
    h[idx] = f2b(fmaxf(val, 0.f));
}

// ---- edge pass, layer 2: 1 head x 64 ch. One wave per edge. ----
// qkvs2 row of 256 bf16: [q 0:64 | k 64:128 | v 128:192 | s 192:256]
__global__ __launch_bounds__(256) void edge_pass2(
    const int* __restrict__ ei, int E,
    const uint16_t* __restrict__ qkvs2,
    float* __restrict__ outAcc,     // [N][64] fp32 accum (d_out)
    float* __restrict__ denom2)     // [N]
{
    int e = (blockIdx.x * 256 + threadIdx.x) >> 6;
    if (e >= E) return;
    int lane = threadIdx.x & 63;
    int src = ei[e];
    int dst = ei[E + e];
    float q = b2f(qkvs2[(size_t)dst * 256 + lane]);
    float k = b2f(qkvs2[(size_t)src * 256 + 64 + lane]);
    float p = q * k;
    p += __shfl_xor(p, 1);
    p += __shfl_xor(p, 2);
    p += __shfl_xor(p, 4);
    p += __shfl_xor(p, 8);
    p += __shfl_xor(p, 16);
    p += __shfl_xor(p, 32);
    float a = __expf(p * 0.125f);                 // 1/sqrt(64)
    if (lane == 0) atomicAdd(&denom2[dst], a);
    float v = b2f(qkvs2[(size_t)src * 256 + 128 + lane]);
    atomicAdd(&outAcc[(size_t)dst * 64 + lane], a * v);
}

// ---- finalize layer 2: out = out/denom + skip (fp32, in-place) ----
__global__ __launch_bounds__(256) void finalize2(
    float* __restrict__ out, const float* __restrict__ denom2,
    const uint16_t* __restrict__ qkvs2, int N)
{
    int idx = blockIdx.x * 256 + threadIdx.x;
    if (idx >= N * 64) return;
    int n = idx >> 6, c = idx & 63;
    float d = denom2[n];
    float inv = (d > 0.f) ? 1.f / d : 0.f;
    out[idx] = out[idx] * inv + b2f(qkvs2[(size_t)n * 256 + 192 + c]);
}

extern "C" void kernel_launch(void* const* d_in, const int* in_sizes, int n_in,
                              void* d_out, int out_size, void* d_ws, size_t ws_size,
                              hipStream_t stream)
{
    const int N = in_sizes[0] / 128;
    const int E = in_sizes[1] / 2;

    const float* x   = (const float*)d_in[0];
    const int*   ei  = (const int*)d_in[1];
    const float* W1q = (const float*)d_in[2],  *b1q = (const float*)d_in[3];
    const float* W1k = (const float*)d_in[4],  *b1k = (const float*)d_in[5];
    const float* W1v = (const float*)d_in[6],  *b1v = (const float*)d_in[7];
    const float* W1s = (const float*)d_in[8],  *b1s = (const float*)d_in[9];
    const float* W2q = (const float*)d_in[10], *b2q = (const float*)d_in[11];
    const float* W2k = (const float*)d_in[12], *b2k = (const float*)d_in[13];
    const float* W2v = (const float*)d_in[14], *b2v = (const float*)d_in[15];
    const float* W2s = (const float*)d_in[16], *b2s = (const float*)d_in[17];

    char* ws = (char*)d_ws;
    size_t off = 0;
    auto alloc = [&](size_t bytes) { size_t r = off; off += (bytes + 255) & ~(size_t)255; return r; };

    uint16_t* qkvs1  = (uint16_t*)(ws + alloc((size_t)N * 512 * 2)); // 51.2 MB
    float*    msg1   = (float*)   (ws + alloc((size_t)N * 128 * 4)); // 25.6 MB
    uint16_t* qkvs2  = (uint16_t*)msg1;                              // overlay (msg1 dead after finalize1)
    float*    denom1 = (float*)   (ws + alloc((size_t)N * 4 * 4));
    uint16_t* h      = (uint16_t*)(ws + alloc((size_t)N * 128 * 2)); // 12.8 MB
    float*    denom2 = (float*)   (ws + alloc((size_t)N * 4));
    uint16_t* Wc1    = (uint16_t*)(ws + alloc((size_t)128 * 512 * 2));
    float*    bc1    = (float*)   (ws + alloc(512 * 4));
    uint16_t* Wc2    = (uint16_t*)(ws + alloc((size_t)128 * 256 * 2));
    float*    bc2    = (float*)   (ws + alloc(256 * 4));
    float*    outF   = (float*)d_out;

    // zero accumulators (harness poisons ws/out once; we must re-init per call)
    hipMemsetAsync(msg1,   0, (size_t)N * 128 * 4, stream);
    hipMemsetAsync(denom1, 0, (size_t)N * 4 * 4,  stream);
    hipMemsetAsync(denom2, 0, (size_t)N * 4,      stream);
    hipMemsetAsync(d_out,  0, (size_t)N * 64 * 4, stream);

    pack_weights<<<(128 * 512 + 512 + 255) / 256, 256, 0, stream>>>(
        W1q, b1q, W1k, b1k, W1v, b1v, W1s, b1s, Wc1, bc1, 128, 128);
    pack_weights<<<(128 * 256 + 256 + 255) / 256, 256, 0, stream>>>(
        W2q, b2q, W2k, b2k, W2v, b2v, W2s, b2s, Wc2, bc2, 128, 64);

    dim3 g1((N + 63) / 64, 8);
    gemm_fused<false><<<g1, 256, 0, stream>>>(x, Wc1, bc1, qkvs1, N, 512);

    edge_pass1<<<(E + 3) / 4, 256, 0, stream>>>(ei, E, qkvs1, msg1, denom1);

    finalize1<<<(N * 128 + 255) / 256, 256, 0, stream>>>(msg1, denom1, qkvs1, h, N);

    dim3 g2((N + 63) / 64, 4);
    gemm_fused<true><<<g2, 256, 0, stream>>>(h, Wc2, bc2, qkvs2, N, 256);

    edge_pass2<<<(E + 3) / 4, 256, 0, stream>>>(ei, E, qkvs2, outF, denom2);

    finalize2<<<(N * 64 + 255) / 256, 256, 0, stream>>>(outF, denom2, qkvs2, N);
}

// Round 2
// 471.374 us; speedup vs baseline: 2.3799x; 2.3799x over previous
//
#include <hip/hip_runtime.h>
#include <hip/hip_bf16.h>
#include <stdint.h>

// ---------------------------------------------------------------------------
// TransformerGNN: two TransformerConv layers (4 heads cat -> relu -> 1 head)
// N=50000 nodes, E=800000 edges, IN=128, HID*HEADS=128, OUT=64
// Round 2: replace atomic scatter edge passes with dst-sorted gather passes.
// ---------------------------------------------------------------------------

__device__ __forceinline__ float b2f(uint16_t u) {
    union { uint32_t i; float f; } x; x.i = ((uint32_t)u) << 16; return x.f;
}
__device__ __forceinline__ uint16_t f2b(float f) {
    __hip_bfloat16 h = __float2bfloat16(f);
    union { __hip_bfloat16 h; uint16_t u; } c; c.h = h; return c.u;
}

// ---- pack 4 weight matrices (fp32) into one concat bf16 [K][4*Cper] + bias ----
__global__ void pack_weights(const float* __restrict__ Wq, const float* __restrict__ bq,
                             const float* __restrict__ Wk, const float* __restrict__ bk,
                             const float* __restrict__ Wv, const float* __restrict__ bv,
                             const float* __restrict__ Ws, const float* __restrict__ bs,
                             uint16_t* __restrict__ Wc, float* __restrict__ bc,
                             int K, int Cper)
{
    int Ntot = 4 * Cper;
    int idx = blockIdx.x * 256 + threadIdx.x;
    int total = K * Ntot;
    if (idx < total) {
        int k = idx / Ntot, col = idx % Ntot;
        int m = col / Cper, c = col % Cper;
        const float* Wm = (m == 0) ? Wq : (m == 1) ? Wk : (m == 2) ? Wv : Ws;
        Wc[idx] = f2b(Wm[k * Cper + c]);
    } else if (idx < total + Ntot) {
        int col = idx - total;
        int m = col / Cper, c = col % Cper;
        const float* bm = (m == 0) ? bq : (m == 1) ? bk : (m == 2) ? bv : bs;
        bc[col] = bm[c];
    }
}

// ---- fused GEMM: Y[M][Ntot] (bf16) = A[M][128] @ Wb[128][Ntot] + bias ----
template <bool ABF16>
__global__ __launch_bounds__(256) void gemm_fused(
    const void* __restrict__ Aptr, const uint16_t* __restrict__ Wb,
    const float* __restrict__ bias, uint16_t* __restrict__ Y,
    int M, int Ntot)
{
    __shared__ float    Alds[64][132];
    __shared__ uint16_t Wlds[128][64];

    const int tid = threadIdx.x;
    const int m0 = blockIdx.x * 64;
    const int n0 = blockIdx.y * 64;

    #pragma unroll
    for (int i = 0; i < 8; ++i) {
        int idx = tid + i * 256;
        int r = idx >> 5, c4 = (idx & 31) << 2;
        int gr = m0 + r;
        float4 v = make_float4(0.f, 0.f, 0.f, 0.f);
        if (gr < M) {
            if (!ABF16) {
                v = *reinterpret_cast<const float4*>((const float*)Aptr + (size_t)gr * 128 + c4);
            } else {
                ushort4 u = *reinterpret_cast<const ushort4*>((const uint16_t*)Aptr + (size_t)gr * 128 + c4);
                v = make_float4(b2f(u.x), b2f(u.y), b2f(u.z), b2f(u.w));
            }
        }
        *reinterpret_cast<float4*>(&Alds[r][c4]) = v;
    }
    #pragma unroll
    for (int i = 0; i < 8; ++i) {
        int idx = tid + i * 256;
        int r = idx >> 4, c4 = (idx & 15) << 2;
        *reinterpret_cast<ushort4*>(&Wlds[r][c4]) =
            *reinterpret_cast<const ushort4*>(Wb + (size_t)r * Ntot + n0 + c4);
    }
    __syncthreads();

    const int ty = tid >> 4, tx = tid & 15;
    float acc[4][4] = {};

    #pragma unroll 2
    for (int kk4 = 0; kk4 < 32; ++kk4) {
        float areg[4][4];
        #pragma unroll
        for (int i = 0; i < 4; ++i)
            *reinterpret_cast<float4*>(areg[i]) =
                *reinterpret_cast<const float4*>(&Alds[ty * 4 + i][kk4 * 4]);
        #pragma unroll
        for (int t = 0; t < 4; ++t) {
            int kk = kk4 * 4 + t;
            ushort4 wu = *reinterpret_cast<const ushort4*>(&Wlds[kk][tx * 4]);
            float w[4] = { b2f(wu.x), b2f(wu.y), b2f(wu.z), b2f(wu.w) };
            #pragma unroll
            for (int i = 0; i < 4; ++i)
                #pragma unroll
                for (int j = 0; j < 4; ++j)
                    acc[i][j] = fmaf(areg[i][t], w[j], acc[i][j]);
        }
    }

    #pragma unroll
    for (int i = 0; i < 4; ++i) {
        int gr = m0 + ty * 4 + i;
        if (gr < M) {
            uint16_t outv[4];
            #pragma unroll
            for (int j = 0; j < 4; ++j)
                outv[j] = f2b(acc[i][j] + bias[n0 + tx * 4 + j]);
            *reinterpret_cast<ushort4*>(Y + (size_t)gr * Ntot + n0 + tx * 4) =
                *reinterpret_cast<ushort4*>(outv);
        }
    }
}

// ---------------------------------------------------------------------------
// Counting sort of edges by dst. cnt -> row_start (exclusive scan) -> scatter
// ---------------------------------------------------------------------------
__global__ __launch_bounds__(256) void hist_kernel(const int* __restrict__ ei, int E,
                                                   int* __restrict__ cnt)
{
    int i = blockIdx.x * 256 + threadIdx.x;
    if (i < E) atomicAdd(&cnt[ei[E + i]], 1);
}

// block b sums cnt[b*1024 .. b*1024+1023]
__global__ __launch_bounds__(256) void scan_block_sums(const int* __restrict__ cnt, int N,
                                                       int* __restrict__ bsums)
{
    __shared__ int red[256];
    int b = blockIdx.x, t = threadIdx.x;
    int base = b * 1024;
    int s = 0;
    #pragma unroll
    for (int j = 0; j < 4; ++j) {
        int i = base + t * 4 + j;
        if (i < N) s += cnt[i];
    }
    red[t] = s; __syncthreads();
    for (int off = 128; off > 0; off >>= 1) {
        if (t < off) red[t] += red[t + off];
        __syncthreads();
    }
    if (t == 0) bsums[b] = red[0];
}

// block b writes row_start[] (+ cursor copy) for its 1024 counters
__global__ __launch_bounds__(256) void scan_write(const int* __restrict__ cnt, int N,
                                                  const int* __restrict__ bsums,
                                                  int* __restrict__ row_start,
                                                  int* __restrict__ cursor)
{
    __shared__ int tsum[256];
    __shared__ int lds2[256];
    int b = blockIdx.x, t = threadIdx.x;

    int part = 0;
    for (int i = t; i < b; i += 256) part += bsums[i];
    tsum[t] = part; __syncthreads();
    for (int off = 128; off > 0; off >>= 1) {
        if (t < off) tsum[t] += tsum[t + off];
        __syncthreads();
    }
    int boff = tsum[0];
    __syncthreads();

    int base = b * 1024;
    int c[4]; int s = 0;
    #pragma unroll
    for (int j = 0; j < 4; ++j) {
        int i = base + t * 4 + j;
        c[j] = (i < N) ? cnt[i] : 0;
        s += c[j];
    }
    lds2[t] = s; __syncthreads();
    for (int off = 1; off < 256; off <<= 1) {
        int v = (t >= off) ? lds2[t - off] : 0;
        __syncthreads();
        lds2[t] += v;
        __syncthreads();
    }
    int excl = lds2[t] - s + boff;
    #pragma unroll
    for (int j = 0; j < 4; ++j) {
        int i = base + t * 4 + j;
        if (i < N) {
            row_start[i] = excl;
            cursor[i] = excl;
            excl += c[j];
            if (i == N - 1) row_start[N] = excl;
        }
    }
}

__global__ __launch_bounds__(256) void scatter_kernel(const int* __restrict__ ei, int E,
                                                      int* __restrict__ cursor,
                                                      int* __restrict__ ssrc)
{
    int i = blockIdx.x * 256 + threadIdx.x;
    if (i < E) {
        int d = ei[E + i];
        int p = atomicAdd(&cursor[d], 1);
        ssrc[p] = ei[i];
    }
}

// ---------------------------------------------------------------------------
// Layer 1 gather pass: one 64-lane wave per dst node; 4 heads x 32ch.
// qkvs row of 512 bf16: [q 0:128 | k 128:256 | v 256:384 | s 384:512]
// Fused finalize: h = relu(acc/den + skip) in bf16.
// ---------------------------------------------------------------------------
__global__ __launch_bounds__(256) void node_pass1(
    const int* __restrict__ ssrc, const int* __restrict__ row_start,
    const uint16_t* __restrict__ qkvs, uint16_t* __restrict__ h, int N)
{
    int node = (blockIdx.x * 256 + threadIdx.x) >> 6;
    if (node >= N) return;
    int lane = threadIdx.x & 63;
    const uint16_t* base = qkvs + (size_t)node * 512;
    uint32_t qw = *reinterpret_cast<const uint32_t*>(base + 2 * lane);
    float q0 = b2f((uint16_t)qw), q1 = b2f((uint16_t)(qw >> 16));

    int beg = row_start[node], end = row_start[node + 1];
    float acc0 = 0.f, acc1 = 0.f, den = 0.f;

    for (int i = beg; i < end; ++i) {
        int s = ssrc[i];
        const uint16_t* sb = qkvs + (size_t)s * 512;
        uint32_t kw = *reinterpret_cast<const uint32_t*>(sb + 128 + 2 * lane);
        uint32_t vw = *reinterpret_cast<const uint32_t*>(sb + 256 + 2 * lane);
        float p = q0 * b2f((uint16_t)kw) + q1 * b2f((uint16_t)(kw >> 16));
        p += __shfl_xor(p, 1);
        p += __shfl_xor(p, 2);
        p += __shfl_xor(p, 4);
        p += __shfl_xor(p, 8);
        float a = __expf(p * 0.17677669529663687f);   // 1/sqrt(32)
        den += a;
        acc0 = fmaf(a, b2f((uint16_t)vw), acc0);
        acc1 = fmaf(a, b2f((uint16_t)(vw >> 16)), acc1);
    }

    float inv = (end > beg) ? 1.f / den : 0.f;
    uint32_t sw = *reinterpret_cast<const uint32_t*>(base + 384 + 2 * lane);
    float r0 = fmaxf(fmaf(acc0, inv, b2f((uint16_t)sw)), 0.f);
    float r1 = fmaxf(fmaf(acc1, inv, b2f((uint16_t)(sw >> 16))), 0.f);
    uint32_t o = ((uint32_t)f2b(r1) << 16) | f2b(r0);
    *reinterpret_cast<uint32_t*>(h + (size_t)node * 128 + 2 * lane) = o;
}

// ---------------------------------------------------------------------------
// Layer 2 gather pass: one wave per dst node; 1 head x 64ch; lane = channel.
// qkvs2 row of 256 bf16: [q 0:64 | k 64:128 | v 128:192 | s 192:256]
// Fused finalize: out = acc/den + skip (fp32).
// ---------------------------------------------------------------------------
__global__ __launch_bounds__(256) void node_pass2(
    const int* __restrict__ ssrc, const int* __restrict__ row_start,
    const uint16_t* __restrict__ qkvs2, float* __restrict__ out, int N)
{
    int node = (blockIdx.x * 256 + threadIdx.x) >> 6;
    if (node >= N) return;
    int lane = threadIdx.x & 63;
    const uint16_t* base = qkvs2 + (size_t)node * 256;
    float q = b2f(base[lane]);

    int beg = row_start[node], end = row_start[node + 1];
    float acc = 0.f, den = 0.f;

    for (int i = beg; i < end; ++i) {
        int s = ssrc[i];
        const uint16_t* sb = qkvs2 + (size_t)s * 256;
        float k = b2f(sb[64 + lane]);
        float v = b2f(sb[128 + lane]);
        float p = q * k;
        p += __shfl_xor(p, 1);
        p += __shfl_xor(p, 2);
        p += __shfl_xor(p, 4);
        p += __shfl_xor(p, 8);
        p += __shfl_xor(p, 16);
        p += __shfl_xor(p, 32);
        float a = __expf(p * 0.125f);                 // 1/sqrt(64)
        den += a;
        acc = fmaf(a, v, acc);
    }

    float inv = (end > beg) ? 1.f / den : 0.f;
    out[(size_t)node * 64 + lane] = fmaf(acc, inv, b2f(base[192 + lane]));
}

extern "C" void kernel_launch(void* const* d_in, const int* in_sizes, int n_in,
                              void* d_out, int out_size, void* d_ws, size_t ws_size,
                              hipStream_t stream)
{
    const int N = in_sizes[0] / 128;
    const int E = in_sizes[1] / 2;

    const float* x   = (const float*)d_in[0];
    const int*   ei  = (const int*)d_in[1];
    const float* W1q = (const float*)d_in[2],  *b1q = (const float*)d_in[3];
    const float* W1k = (const float*)d_in[4],  *b1k = (const float*)d_in[5];
    const float* W1v = (const float*)d_in[6],  *b1v = (const float*)d_in[7];
    const float* W1s = (const float*)d_in[8],  *b1s = (const float*)d_in[9];
    const float* W2q = (const float*)d_in[10], *b2q = (const float*)d_in[11];
    const float* W2k = (const float*)d_in[12], *b2k = (const float*)d_in[13];
    const float* W2v = (const float*)d_in[14], *b2v = (const float*)d_in[15];
    const float* W2s = (const float*)d_in[16], *b2s = (const float*)d_in[17];

    char* ws = (char*)d_ws;
    size_t off = 0;
    auto alloc = [&](size_t bytes) { size_t r = off; off += (bytes + 255) & ~(size_t)255; return r; };

    uint16_t* qkvs1    = (uint16_t*)(ws + alloc((size_t)N * 512 * 2)); // 51.2 MB
    uint16_t* qkvs2    = qkvs1;   // overlay: qkvs1 dead before gemm2 writes qkvs2
    uint16_t* h        = (uint16_t*)(ws + alloc((size_t)N * 128 * 2)); // 12.8 MB
    int*      ssrc     = (int*)   (ws + alloc((size_t)E * 4));         // 3.2 MB
    int*      cnt      = (int*)   (ws + alloc((size_t)N * 4));
    int*      row_start= (int*)   (ws + alloc((size_t)(N + 1) * 4));
    int*      cursor   = (int*)   (ws + alloc((size_t)N * 4));
    int*      bsums    = (int*)   (ws + alloc(1024 * 4));
    uint16_t* Wc1      = (uint16_t*)(ws + alloc((size_t)128 * 512 * 2));
    float*    bc1      = (float*)  (ws + alloc(512 * 4));
    uint16_t* Wc2      = (uint16_t*)(ws + alloc((size_t)128 * 256 * 2));
    float*    bc2      = (float*)  (ws + alloc(256 * 4));
    float*    outF     = (float*)d_out;

    const int nb = (N + 1023) / 1024;

    hipMemsetAsync(cnt, 0, (size_t)N * 4, stream);

    pack_weights<<<(128 * 512 + 512 + 255) / 256, 256, 0, stream>>>(
        W1q, b1q, W1k, b1k, W1v, b1v, W1s, b1s, Wc1, bc1, 128, 128);
    pack_weights<<<(128 * 256 + 256 + 255) / 256, 256, 0, stream>>>(
        W2q, b2q, W2k, b2k, W2v, b2v, W2s, b2s, Wc2, bc2, 128, 64);

    // counting sort by dst (src-only payload; reused by both layers)
    hist_kernel<<<(E + 255) / 256, 256, 0, stream>>>(ei, E, cnt);
    scan_block_sums<<<nb, 256, 0, stream>>>(cnt, N, bsums);
    scan_write<<<nb, 256, 0, stream>>>(cnt, N, bsums, row_start, cursor);
    scatter_kernel<<<(E + 255) / 256, 256, 0, stream>>>(ei, E, cursor, ssrc);

    // layer 1
    dim3 g1((N + 63) / 64, 8);
    gemm_fused<false><<<g1, 256, 0, stream>>>(x, Wc1, bc1, qkvs1, N, 512);
    node_pass1<<<(N * 64 + 255) / 256, 256, 0, stream>>>(ssrc, row_start, qkvs1, h, N);

    // layer 2 (qkvs2 overlays qkvs1; qkvs1 is dead after node_pass1)
    dim3 g2((N + 63) / 64, 4);
    gemm_fused<true><<<g2, 256, 0, stream>>>(h, Wc2, bc2, qkvs2, N, 256);
    node_pass2<<<(N * 64 + 255) / 256, 256, 0, stream>>>(ssrc, row_start, qkvs2, outF, N);
}

// Round 3
// 396.763 us; speedup vs baseline: 2.8274x; 1.1880x over previous
//
#include <hip/hip_runtime.h>
#include <hip/hip_bf16.h>
#include <stdint.h>

// ---------------------------------------------------------------------------
// TransformerGNN: two TransformerConv layers (4 heads cat -> relu -> 1 head)
// N=50000 nodes, E=800000 edges, IN=128, HID*HEADS=128, OUT=64
// Round 3: bf16 MFMA GEMMs (16x16x32), XOR-swizzled LDS, W pre-transposed.
// ---------------------------------------------------------------------------

typedef __attribute__((ext_vector_type(8))) short short8;
typedef __attribute__((ext_vector_type(4))) float floatx4;

__device__ __forceinline__ float b2f(uint16_t u) {
    union { uint32_t i; float f; } x; x.i = ((uint32_t)u) << 16; return x.f;
}
__device__ __forceinline__ uint16_t f2b(float f) {
    __hip_bfloat16 h = __float2bfloat16(f);
    union { __hip_bfloat16 h; uint16_t u; } c; c.h = h; return c.u;
}

// ---- pack 4 weight matrices (fp32 [K][Cper]) into transposed concat bf16
// ---- Wt[Ntot][K] (Ntot = 4*Cper), plus fp32 bias concat bc[Ntot].
__global__ void pack_weights(const float* __restrict__ Wq, const float* __restrict__ bq,
                             const float* __restrict__ Wk, const float* __restrict__ bk,
                             const float* __restrict__ Wv, const float* __restrict__ bv,
                             const float* __restrict__ Ws, const float* __restrict__ bs,
                             uint16_t* __restrict__ Wt, float* __restrict__ bc,
                             int K, int Cper)
{
    int Ntot = 4 * Cper;
    int idx = blockIdx.x * 256 + threadIdx.x;
    int total = K * Ntot;
    if (idx < total) {
        int col = idx / K, k = idx % K;          // Wt[col][k]
        int m = col / Cper, c = col % Cper;
        const float* Wm = (m == 0) ? Wq : (m == 1) ? Wk : (m == 2) ? Wv : Ws;
        Wt[idx] = f2b(Wm[k * Cper + c]);
    } else if (idx < total + Ntot) {
        int col = idx - total;
        int m = col / Cper, c = col % Cper;
        const float* bm = (m == 0) ? bq : (m == 1) ? bk : (m == 2) ? bv : bs;
        bc[col] = bm[c];
    }
}

// ---------------------------------------------------------------------------
// MFMA GEMM: Y[M][Ntot] (bf16) = A[M][128] @ W[128][Ntot] + bias
// W passed transposed: Wt[Ntot][128] bf16. A fp32 (layer1) or bf16 (layer2).
// Block: 256 thr / 4 waves; BM=64 (16 rows per wave), BN=256, K=128.
// LDS tiles XOR-swizzled (byte ^= (row&7)<<4) for conflict-free ds_read_b128.
// ---------------------------------------------------------------------------
template <bool ABF16>
__global__ __launch_bounds__(256) void gemm_mfma(
    const void* __restrict__ Aptr, const uint16_t* __restrict__ Wt,
    const float* __restrict__ bias, uint16_t* __restrict__ Y,
    int M, int Ntot)
{
    __shared__ __align__(16) char Ab[64 * 256];    // 64 rows x 128 bf16 (256B/row)
    __shared__ __align__(16) char Bb[256 * 256];   // 256 Wt-rows x 128 bf16

    const int tid = threadIdx.x;
    const int m0 = blockIdx.x * 64;
    const int n0 = blockIdx.y * 256;

    // stage A: 1024 granules of 16B (8 bf16), swizzled
    #pragma unroll
    for (int i = 0; i < 4; ++i) {
        int g = tid + i * 256;
        int r = g >> 4, c8 = g & 15;
        int gr = m0 + r;
        uint16_t tmp[8];
        if (gr < M) {
            if (!ABF16) {
                const float* ap = (const float*)Aptr + (size_t)gr * 128 + c8 * 8;
                float4 v0 = *(const float4*)ap;
                float4 v1 = *(const float4*)(ap + 4);
                tmp[0] = f2b(v0.x); tmp[1] = f2b(v0.y); tmp[2] = f2b(v0.z); tmp[3] = f2b(v0.w);
                tmp[4] = f2b(v1.x); tmp[5] = f2b(v1.y); tmp[6] = f2b(v1.z); tmp[7] = f2b(v1.w);
            } else {
                *(short8*)tmp = *(const short8*)((const uint16_t*)Aptr + (size_t)gr * 128 + c8 * 8);
            }
        } else {
            #pragma unroll
            for (int j = 0; j < 8; ++j) tmp[j] = 0;
        }
        int off = r * 256 + ((c8 * 16) ^ ((r & 7) << 4));
        *(short8*)(Ab + off) = *(short8*)tmp;
    }
    // stage Wt tile: 4096 granules of 16B, swizzled
    #pragma unroll
    for (int i = 0; i < 16; ++i) {
        int g = tid + i * 256;
        int n = g >> 4, c8 = g & 15;
        short8 v = *(const short8*)(Wt + (size_t)(n0 + n) * 128 + c8 * 8);
        int off = n * 256 + ((c8 * 16) ^ ((n & 7) << 4));
        *(short8*)(Bb + off) = v;
    }
    __syncthreads();

    const int wv = tid >> 6, lane = tid & 63;
    const int lrow = lane & 15, kc = lane >> 4;    // kc = k-chunk 0..3

    // A fragments: row = wv*16 + lrow, 4 k-steps of 32 (lane owns 8 bf16 each)
    short8 aF[4];
    const int ar = wv * 16 + lrow;
    #pragma unroll
    for (int ks = 0; ks < 4; ++ks) {
        int off = ar * 256 + ((ks * 64 + kc * 16) ^ ((ar & 7) << 4));
        aF[ks] = *(const short8*)(Ab + off);
    }

    floatx4 acc[16];
    #pragma unroll
    for (int t = 0; t < 16; ++t) acc[t] = (floatx4){0.f, 0.f, 0.f, 0.f};

    #pragma unroll
    for (int t = 0; t < 16; ++t) {
        const int nr = t * 16 + lrow;
        #pragma unroll
        for (int ks = 0; ks < 4; ++ks) {
            int off = nr * 256 + ((ks * 64 + kc * 16) ^ ((nr & 7) << 4));
            short8 bF = *(const short8*)(Bb + off);
            acc[t] = __builtin_amdgcn_mfma_f32_16x16x32_bf16(aF[ks], bF, acc[t], 0, 0, 0);
        }
    }

    // epilogue: C/D layout col=lane&15, row=(lane>>4)*4+j  (+bias, bf16 store)
    const int orow = m0 + wv * 16 + kc * 4;
    #pragma unroll
    for (int t = 0; t < 16; ++t) {
        int col = n0 + t * 16 + lrow;
        float bs = bias[col];
        #pragma unroll
        for (int j = 0; j < 4; ++j) {
            int gr = orow + j;
            if (gr < M) Y[(size_t)gr * Ntot + col] = f2b(acc[t][j] + bs);
        }
    }
}

// ---------------------------------------------------------------------------
// Counting sort of edges by dst. cnt -> row_start (exclusive scan) -> scatter
// ---------------------------------------------------------------------------
__global__ __launch_bounds__(256) void hist_kernel(const int* __restrict__ ei, int E,
                                                   int* __restrict__ cnt)
{
    int i = blockIdx.x * 256 + threadIdx.x;
    if (i < E) atomicAdd(&cnt[ei[E + i]], 1);
}

__global__ __launch_bounds__(256) void scan_block_sums(const int* __restrict__ cnt, int N,
                                                       int* __restrict__ bsums)
{
    __shared__ int red[256];
    int b = blockIdx.x, t = threadIdx.x;
    int base = b * 1024;
    int s = 0;
    #pragma unroll
    for (int j = 0; j < 4; ++j) {
        int i = base + t * 4 + j;
        if (i < N) s += cnt[i];
    }
    red[t] = s; __syncthreads();
    for (int off = 128; off > 0; off >>= 1) {
        if (t < off) red[t] += red[t + off];
        __syncthreads();
    }
    if (t == 0) bsums[b] = red[0];
}

__global__ __launch_bounds__(256) void scan_write(const int* __restrict__ cnt, int N,
                                                  const int* __restrict__ bsums,
                                                  int* __restrict__ row_start,
                                                  int* __restrict__ cursor)
{
    __shared__ int tsum[256];
    __shared__ int lds2[256];
    int b = blockIdx.x, t = threadIdx.x;

    int part = 0;
    for (int i = t; i < b; i += 256) part += bsums[i];
    tsum[t] = part; __syncthreads();
    for (int off = 128; off > 0; off >>= 1) {
        if (t < off) tsum[t] += tsum[t + off];
        __syncthreads();
    }
    int boff = tsum[0];
    __syncthreads();

    int base = b * 1024;
    int c[4]; int s = 0;
    #pragma unroll
    for (int j = 0; j < 4; ++j) {
        int i = base + t * 4 + j;
        c[j] = (i < N) ? cnt[i] : 0;
        s += c[j];
    }
    lds2[t] = s; __syncthreads();
    for (int off = 1; off < 256; off <<= 1) {
        int v = (t >= off) ? lds2[t - off] : 0;
        __syncthreads();
        lds2[t] += v;
        __syncthreads();
    }
    int excl = lds2[t] - s + boff;
    #pragma unroll
    for (int j = 0; j < 4; ++j) {
        int i = base + t * 4 + j;
        if (i < N) {
            row_start[i] = excl;
            cursor[i] = excl;
            excl += c[j];
            if (i == N - 1) row_start[N] = excl;
        }
    }
}

__global__ __launch_bounds__(256) void scatter_kernel(const int* __restrict__ ei, int E,
                                                      int* __restrict__ cursor,
                                                      int* __restrict__ ssrc)
{
    int i = blockIdx.x * 256 + threadIdx.x;
    if (i < E) {
        int d = ei[E + i];
        int p = atomicAdd(&cursor[d], 1);
        ssrc[p] = ei[i];
    }
}

// ---------------------------------------------------------------------------
// Layer 1 gather pass: one 64-lane wave per dst node; 4 heads x 32ch.
// qkvs row of 512 bf16: [q 0:128 | k 128:256 | v 256:384 | s 384:512]
// ---------------------------------------------------------------------------
__global__ __launch_bounds__(256) void node_pass1(
    const int* __restrict__ ssrc, const int* __restrict__ row_start,
    const uint16_t* __restrict__ qkvs, uint16_t* __restrict__ h, int N)
{
    int node = (blockIdx.x * 256 + threadIdx.x) >> 6;
    if (node >= N) return;
    int lane = threadIdx.x & 63;
    const uint16_t* base = qkvs + (size_t)node * 512;
    uint32_t qw = *reinterpret_cast<const uint32_t*>(base + 2 * lane);
    float q0 = b2f((uint16_t)qw), q1 = b2f((uint16_t)(qw >> 16));

    int beg = row_start[node], end = row_start[node + 1];
    float acc0 = 0.f, acc1 = 0.f, den = 0.f;

    for (int i = beg; i < end; ++i) {
        int s = ssrc[i];
        const uint16_t* sb = qkvs + (size_t)s * 512;
        uint32_t kw = *reinterpret_cast<const uint32_t*>(sb + 128 + 2 * lane);
        uint32_t vw = *reinterpret_cast<const uint32_t*>(sb + 256 + 2 * lane);
        float p = q0 * b2f((uint16_t)kw) + q1 * b2f((uint16_t)(kw >> 16));
        p += __shfl_xor(p, 1);
        p += __shfl_xor(p, 2);
        p += __shfl_xor(p, 4);
        p += __shfl_xor(p, 8);
        float a = __expf(p * 0.17677669529663687f);   // 1/sqrt(32)
        den += a;
        acc0 = fmaf(a, b2f((uint16_t)vw), acc0);
        acc1 = fmaf(a, b2f((uint16_t)(vw >> 16)), acc1);
    }

    float inv = (end > beg) ? 1.f / den : 0.f;
    uint32_t sw = *reinterpret_cast<const uint32_t*>(base + 384 + 2 * lane);
    float r0 = fmaxf(fmaf(acc0, inv, b2f((uint16_t)sw)), 0.f);
    float r1 = fmaxf(fmaf(acc1, inv, b2f((uint16_t)(sw >> 16))), 0.f);
    uint32_t o = ((uint32_t)f2b(r1) << 16) | f2b(r0);
    *reinterpret_cast<uint32_t*>(h + (size_t)node * 128 + 2 * lane) = o;
}

// ---------------------------------------------------------------------------
// Layer 2 gather pass: one wave per dst node; 1 head x 64ch; lane = channel.
// qkvs2 row of 256 bf16: [q 0:64 | k 64:128 | v 128:192 | s 192:256]
// ---------------------------------------------------------------------------
__global__ __launch_bounds__(256) void node_pass2(
    const int* __restrict__ ssrc, const int* __restrict__ row_start,
    const uint16_t* __restrict__ qkvs2, float* __restrict__ out, int N)
{
    int node = (blockIdx.x * 256 + threadIdx.x) >> 6;
    if (node >= N) return;
    int lane = threadIdx.x & 63;
    const uint16_t* base = qkvs2 + (size_t)node * 256;
    float q = b2f(base[lane]);

    int beg = row_start[node], end = row_start[node + 1];
    float acc = 0.f, den = 0.f;

    for (int i = beg; i < end; ++i) {
        int s = ssrc[i];
        const uint16_t* sb = qkvs2 + (size_t)s * 256;
        float k = b2f(sb[64 + lane]);
        float v = b2f(sb[128 + lane]);
        float p = q * k;
        p += __shfl_xor(p, 1);
        p += __shfl_xor(p, 2);
        p += __shfl_xor(p, 4);
        p += __shfl_xor(p, 8);
        p += __shfl_xor(p, 16);
        p += __shfl_xor(p, 32);
        float a = __expf(p * 0.125f);                 // 1/sqrt(64)
        den += a;
        acc = fmaf(a, v, acc);
    }

    float inv = (end > beg) ? 1.f / den : 0.f;
    out[(size_t)node * 64 + lane] = fmaf(acc, inv, b2f(base[192 + lane]));
}

extern "C" void kernel_launch(void* const* d_in, const int* in_sizes, int n_in,
                              void* d_out, int out_size, void* d_ws, size_t ws_size,
                              hipStream_t stream)
{
    const int N = in_sizes[0] / 128;
    const int E = in_sizes[1] / 2;

    const float* x   = (const float*)d_in[0];
    const int*   ei  = (const int*)d_in[1];
    const float* W1q = (const float*)d_in[2],  *b1q = (const float*)d_in[3];
    const float* W1k = (const float*)d_in[4],  *b1k = (const float*)d_in[5];
    const float* W1v = (const float*)d_in[6],  *b1v = (const float*)d_in[7];
    const float* W1s = (const float*)d_in[8],  *b1s = (const float*)d_in[9];
    const float* W2q = (const float*)d_in[10], *b2q = (const float*)d_in[11];
    const float* W2k = (const float*)d_in[12], *b2k = (const float*)d_in[13];
    const float* W2v = (const float*)d_in[14], *b2v = (const float*)d_in[15];
    const float* W2s = (const float*)d_in[16], *b2s = (const float*)d_in[17];

    char* ws = (char*)d_ws;
    size_t off = 0;
    auto alloc = [&](size_t bytes) { size_t r = off; off += (bytes + 255) & ~(size_t)255; return r; };

    uint16_t* qkvs1    = (uint16_t*)(ws + alloc((size_t)N * 512 * 2)); // 51.2 MB
    uint16_t* qkvs2    = qkvs1;   // overlay: qkvs1 dead before gemm2 writes qkvs2
    uint16_t* h        = (uint16_t*)(ws + alloc((size_t)N * 128 * 2)); // 12.8 MB
    int*      ssrc     = (int*)   (ws + alloc((size_t)E * 4));         // 3.2 MB
    int*      cnt      = (int*)   (ws + alloc((size_t)N * 4));
    int*      row_start= (int*)   (ws + alloc((size_t)(N + 1) * 4));
    int*      cursor   = (int*)   (ws + alloc((size_t)N * 4));
    int*      bsums    = (int*)   (ws + alloc(1024 * 4));
    uint16_t* Wt1      = (uint16_t*)(ws + alloc((size_t)128 * 512 * 2));
    float*    bc1      = (float*)  (ws + alloc(512 * 4));
    uint16_t* Wt2      = (uint16_t*)(ws + alloc((size_t)128 * 256 * 2));
    float*    bc2      = (float*)  (ws + alloc(256 * 4));
    float*    outF     = (float*)d_out;

    const int nb = (N + 1023) / 1024;

    hipMemsetAsync(cnt, 0, (size_t)N * 4, stream);

    pack_weights<<<(128 * 512 + 512 + 255) / 256, 256, 0, stream>>>(
        W1q, b1q, W1k, b1k, W1v, b1v, W1s, b1s, Wt1, bc1, 128, 128);
    pack_weights<<<(128 * 256 + 256 + 255) / 256, 256, 0, stream>>>(
        W2q, b2q, W2k, b2k, W2v, b2v, W2s, b2s, Wt2, bc2, 128, 64);

    // counting sort by dst (src-only payload; reused by both layers)
    hist_kernel<<<(E + 255) / 256, 256, 0, stream>>>(ei, E, cnt);
    scan_block_sums<<<nb, 256, 0, stream>>>(cnt, N, bsums);
    scan_write<<<nb, 256, 0, stream>>>(cnt, N, bsums, row_start, cursor);
    scatter_kernel<<<(E + 255) / 256, 256, 0, stream>>>(ei, E, cursor, ssrc);

    // layer 1: qkvs1 = x @ W1 + b1 (bf16), then gather
    dim3 g1((N + 63) / 64, 2);
    gemm_mfma<false><<<g1, 256, 0, stream>>>(x, Wt1, bc1, qkvs1, N, 512);
    node_pass1<<<(N * 64 + 255) / 256, 256, 0, stream>>>(ssrc, row_start, qkvs1, h, N);

    // layer 2 (qkvs2 overlays qkvs1; qkvs1 dead after node_pass1)
    dim3 g2((N + 63) / 64, 1);
    gemm_mfma<true><<<g2, 256, 0, stream>>>(h, Wt2, bc2, qkvs2, N, 256);
    node_pass2<<<(N * 64 + 255) / 256, 256, 0, stream>>>(ssrc, row_start, qkvs2, outF, N);
}

// Round 4
// 332.953 us; speedup vs baseline: 3.3693x; 1.1916x over previous
//
#include <hip/hip_runtime.h>
#include <hip/hip_bf16.h>
#include <stdint.h>

// ---------------------------------------------------------------------------
// TransformerGNN: two TransformerConv layers (4 heads cat -> relu -> 1 head)
// N=50000 nodes, E=800000 edges, IN=128, HID*HEADS=128, OUT=64
// Round 4: node passes get 8-deep gather batching (ILP) + k/v column
// interleave (packed at weight-pack time) so each edge needs 1 load.
// ---------------------------------------------------------------------------

typedef __attribute__((ext_vector_type(8))) short short8;
typedef __attribute__((ext_vector_type(4))) float floatx4;

__device__ __forceinline__ float b2f(uint16_t u) {
    union { uint32_t i; float f; } x; x.i = ((uint32_t)u) << 16; return x.f;
}
__device__ __forceinline__ uint16_t f2b(float f) {
    __hip_bfloat16 h = __float2bfloat16(f);
    union { __hip_bfloat16 h; uint16_t u; } c; c.h = h; return c.u;
}

// ---------------------------------------------------------------------------
// pack 4 weight matrices (fp32 [K][Cper]) into transposed concat bf16
// Wt[Ntot][K] with a k/v-interleaved column layout, plus fp32 bias bc[Ntot].
// LAYER 1 (Cper=128): q->c | k->128+4*(c/2)+(c&1) | v->130+4*(c/2)+(c&1) | s->384+c
// LAYER 2 (Cper=64) : q->c | k->64+2c           | v->65+2c             | s->192+c
// ---------------------------------------------------------------------------
template <int LAYER>
__global__ void pack_weights(const float* __restrict__ Wq, const float* __restrict__ bq,
                             const float* __restrict__ Wk, const float* __restrict__ bk,
                             const float* __restrict__ Wv, const float* __restrict__ bv,
                             const float* __restrict__ Ws, const float* __restrict__ bs,
                             uint16_t* __restrict__ Wt, float* __restrict__ bc,
                             int K, int Cper)
{
    int Ntot = 4 * Cper;
    int idx = blockIdx.x * 256 + threadIdx.x;
    int total = K * Ntot;

    auto mapcol = [&](int m, int c) -> int {
        if (LAYER == 1) {
            if (m == 0) return c;
            if (m == 1) return 128 + 4 * (c >> 1) + (c & 1);
            if (m == 2) return 130 + 4 * (c >> 1) + (c & 1);
            return 384 + c;
        } else {
            if (m == 0) return c;
            if (m == 1) return 64 + 2 * c;
            if (m == 2) return 65 + 2 * c;
            return 192 + c;
        }
    };

    if (idx < total) {
        int m = idx / (Cper * K);
        int rem = idx - m * (Cper * K);
        int c = rem / K, k = rem % K;
        const float* Wm = (m == 0) ? Wq : (m == 1) ? Wk : (m == 2) ? Wv : Ws;
        Wt[(size_t)mapcol(m, c) * K + k] = f2b(Wm[k * Cper + c]);
    } else if (idx < total + Ntot) {
        int i = idx - total;
        int m = i / Cper, c = i % Cper;
        const float* bm = (m == 0) ? bq : (m == 1) ? bk : (m == 2) ? bv : bs;
        bc[mapcol(m, c)] = bm[c];
    }
}

// ---------------------------------------------------------------------------
// MFMA GEMM: Y[M][Ntot] (bf16) = A[M][128] @ W[128][Ntot] + bias
// W passed transposed: Wt[Ntot][128] bf16. A fp32 (layer1) or bf16 (layer2).
// Block: 256 thr / 4 waves; BM=64 (16 rows per wave), BN=256, K=128.
// LDS tiles XOR-swizzled (byte ^= (row&7)<<4) for conflict-free ds_read_b128.
// ---------------------------------------------------------------------------
template <bool ABF16>
__global__ __launch_bounds__(256) void gemm_mfma(
    const void* __restrict__ Aptr, const uint16_t* __restrict__ Wt,
    const float* __restrict__ bias, uint16_t* __restrict__ Y,
    int M, int Ntot)
{
    __shared__ __align__(16) char Ab[64 * 256];    // 64 rows x 128 bf16 (256B/row)
    __shared__ __align__(16) char Bb[256 * 256];   // 256 Wt-rows x 128 bf16

    const int tid = threadIdx.x;
    const int m0 = blockIdx.x * 64;
    const int n0 = blockIdx.y * 256;

    #pragma unroll
    for (int i = 0; i < 4; ++i) {
        int g = tid + i * 256;
        int r = g >> 4, c8 = g & 15;
        int gr = m0 + r;
        uint16_t tmp[8];
        if (gr < M) {
            if (!ABF16) {
                const float* ap = (const float*)Aptr + (size_t)gr * 128 + c8 * 8;
                float4 v0 = *(const float4*)ap;
                float4 v1 = *(const float4*)(ap + 4);
                tmp[0] = f2b(v0.x); tmp[1] = f2b(v0.y); tmp[2] = f2b(v0.z); tmp[3] = f2b(v0.w);
                tmp[4] = f2b(v1.x); tmp[5] = f2b(v1.y); tmp[6] = f2b(v1.z); tmp[7] = f2b(v1.w);
            } else {
                *(short8*)tmp = *(const short8*)((const uint16_t*)Aptr + (size_t)gr * 128 + c8 * 8);
            }
        } else {
            #pragma unroll
            for (int j = 0; j < 8; ++j) tmp[j] = 0;
        }
        int off = r * 256 + ((c8 * 16) ^ ((r & 7) << 4));
        *(short8*)(Ab + off) = *(short8*)tmp;
    }
    #pragma unroll
    for (int i = 0; i < 16; ++i) {
        int g = tid + i * 256;
        int n = g >> 4, c8 = g & 15;
        short8 v = *(const short8*)(Wt + (size_t)(n0 + n) * 128 + c8 * 8);
        int off = n * 256 + ((c8 * 16) ^ ((n & 7) << 4));
        *(short8*)(Bb + off) = v;
    }
    __syncthreads();

    const int wv = tid >> 6, lane = tid & 63;
    const int lrow = lane & 15, kc = lane >> 4;    // kc = k-chunk 0..3

    short8 aF[4];
    const int ar = wv * 16 + lrow;
    #pragma unroll
    for (int ks = 0; ks < 4; ++ks) {
        int off = ar * 256 + ((ks * 64 + kc * 16) ^ ((ar & 7) << 4));
        aF[ks] = *(const short8*)(Ab + off);
    }

    floatx4 acc[16];
    #pragma unroll
    for (int t = 0; t < 16; ++t) acc[t] = (floatx4){0.f, 0.f, 0.f, 0.f};

    #pragma unroll
    for (int t = 0; t < 16; ++t) {
        const int nr = t * 16 + lrow;
        #pragma unroll
        for (int ks = 0; ks < 4; ++ks) {
            int off = nr * 256 + ((ks * 64 + kc * 16) ^ ((nr & 7) << 4));
            short8 bF = *(const short8*)(Bb + off);
            acc[t] = __builtin_amdgcn_mfma_f32_16x16x32_bf16(aF[ks], bF, acc[t], 0, 0, 0);
        }
    }

    const int orow = m0 + wv * 16 + kc * 4;
    #pragma unroll
    for (int t = 0; t < 16; ++t) {
        int col = n0 + t * 16 + lrow;
        float bs = bias[col];
        #pragma unroll
        for (int j = 0; j < 4; ++j) {
            int gr = orow + j;
            if (gr < M) Y[(size_t)gr * Ntot + col] = f2b(acc[t][j] + bs);
        }
    }
}

// ---------------------------------------------------------------------------
// Counting sort of edges by dst. cnt -> row_start (exclusive scan) -> scatter
// ---------------------------------------------------------------------------
__global__ __launch_bounds__(256) void hist_kernel(const int* __restrict__ ei, int E,
                                                   int* __restrict__ cnt)
{
    int i = blockIdx.x * 256 + threadIdx.x;
    if (i < E) atomicAdd(&cnt[ei[E + i]], 1);
}

__global__ __launch_bounds__(256) void scan_block_sums(const int* __restrict__ cnt, int N,
                                                       int* __restrict__ bsums)
{
    __shared__ int red[256];
    int b = blockIdx.x, t = threadIdx.x;
    int base = b * 1024;
    int s = 0;
    #pragma unroll
    for (int j = 0; j < 4; ++j) {
        int i = base + t * 4 + j;
        if (i < N) s += cnt[i];
    }
    red[t] = s; __syncthreads();
    for (int off = 128; off > 0; off >>= 1) {
        if (t < off) red[t] += red[t + off];
        __syncthreads();
    }
    if (t == 0) bsums[b] = red[0];
}

__global__ __launch_bounds__(256) void scan_write(const int* __restrict__ cnt, int N,
                                                  const int* __restrict__ bsums,
                                                  int* __restrict__ row_start,
                                                  int* __restrict__ cursor)
{
    __shared__ int tsum[256];
    __shared__ int lds2[256];
    int b = blockIdx.x, t = threadIdx.x;

    int part = 0;
    for (int i = t; i < b; i += 256) part += bsums[i];
    tsum[t] = part; __syncthreads();
    for (int off = 128; off > 0; off >>= 1) {
        if (t < off) tsum[t] += tsum[t + off];
        __syncthreads();
    }
    int boff = tsum[0];
    __syncthreads();

    int base = b * 1024;
    int c[4]; int s = 0;
    #pragma unroll
    for (int j = 0; j < 4; ++j) {
        int i = base + t * 4 + j;
        c[j] = (i < N) ? cnt[i] : 0;
        s += c[j];
    }
    lds2[t] = s; __syncthreads();
    for (int off = 1; off < 256; off <<= 1) {
        int v = (t >= off) ? lds2[t - off] : 0;
        __syncthreads();
        lds2[t] += v;
        __syncthreads();
    }
    int excl = lds2[t] - s + boff;
    #pragma unroll
    for (int j = 0; j < 4; ++j) {
        int i = base + t * 4 + j;
        if (i < N) {
            row_start[i] = excl;
            cursor[i] = excl;
            excl += c[j];
            if (i == N - 1) row_start[N] = excl;
        }
    }
}

__global__ __launch_bounds__(256) void scatter_kernel(const int* __restrict__ ei, int E,
                                                      int* __restrict__ cursor,
                                                      int* __restrict__ ssrc)
{
    int i = blockIdx.x * 256 + threadIdx.x;
    if (i < E) {
        int d = ei[E + i];
        int p = atomicAdd(&cursor[d], 1);
        ssrc[p] = ei[i];
    }
}

// ---------------------------------------------------------------------------
// Layer 1 gather pass: one 64-lane wave per dst node; 4 heads x 32ch.
// qkvs row of 512 bf16: [q 0:128 | kv interleaved 128:384 | s 384:512]
//   granule at 128+4g: [k_{2g}, k_{2g+1}, v_{2g}, v_{2g+1}]
// 8-deep gather batching for memory-level parallelism.
// ---------------------------------------------------------------------------
__global__ __launch_bounds__(256) void node_pass1(
    const int* __restrict__ ssrc, const int* __restrict__ row_start,
    const uint16_t* __restrict__ qkvs, uint16_t* __restrict__ h, int N)
{
    int node = (blockIdx.x * 256 + threadIdx.x) >> 6;
    if (node >= N) return;
    int lane = threadIdx.x & 63;
    const uint16_t* base = qkvs + (size_t)node * 512;
    uint32_t qw = *reinterpret_cast<const uint32_t*>(base + 2 * lane);
    float q0 = b2f((uint16_t)qw), q1 = b2f((uint16_t)(qw >> 16));

    int beg = row_start[node], end = row_start[node + 1];
    float acc0 = 0.f, acc1 = 0.f, den = 0.f;

    for (int i = beg; i < end; i += 8) {
        int nb = end - i;                      // wave-uniform
        uint2 kv[8];
        #pragma unroll
        for (int j = 0; j < 8; ++j) {
            int idx = i + ((j < nb) ? j : 0);  // pad replays first edge (safe addr)
            const uint16_t* sb = qkvs + (size_t)ssrc[idx] * 512;
            kv[j] = *reinterpret_cast<const uint2*>(sb + 128 + 4 * lane);
        }
        #pragma unroll
        for (int j = 0; j < 8; ++j) {
            if (j < nb) {
                float p = q0 * b2f((uint16_t)kv[j].x) + q1 * b2f((uint16_t)(kv[j].x >> 16));
                p += __shfl_xor(p, 1);
                p += __shfl_xor(p, 2);
                p += __shfl_xor(p, 4);
                p += __shfl_xor(p, 8);
                float a = __expf(p * 0.17677669529663687f);   // 1/sqrt(32)
                den += a;
                acc0 = fmaf(a, b2f((uint16_t)kv[j].y), acc0);
                acc1 = fmaf(a, b2f((uint16_t)(kv[j].y >> 16)), acc1);
            }
        }
    }

    float inv = (end > beg) ? 1.f / den : 0.f;
    uint32_t sw = *reinterpret_cast<const uint32_t*>(base + 384 + 2 * lane);
    float r0 = fmaxf(fmaf(acc0, inv, b2f((uint16_t)sw)), 0.f);
    float r1 = fmaxf(fmaf(acc1, inv, b2f((uint16_t)(sw >> 16))), 0.f);
    uint32_t o = ((uint32_t)f2b(r1) << 16) | f2b(r0);
    *reinterpret_cast<uint32_t*>(h + (size_t)node * 128 + 2 * lane) = o;
}

// ---------------------------------------------------------------------------
// Layer 2 gather pass: one wave per dst node; 1 head x 64ch; lane = channel.
// qkvs2 row of 256 bf16: [q 0:64 | kv interleaved 64:192 | s 192:256]
//   pair at 64+2c: [k_c, v_c]
// ---------------------------------------------------------------------------
__global__ __launch_bounds__(256) void node_pass2(
    const int* __restrict__ ssrc, const int* __restrict__ row_start,
    const uint16_t* __restrict__ qkvs2, float* __restrict__ out, int N)
{
    int node = (blockIdx.x * 256 + threadIdx.x) >> 6;
    if (node >= N) return;
    int lane = threadIdx.x & 63;
    const uint16_t* base = qkvs2 + (size_t)node * 256;
    float q = b2f(base[lane]);

    int beg = row_start[node], end = row_start[node + 1];
    float acc = 0.f, den = 0.f;

    for (int i = beg; i < end; i += 8) {
        int nb = end - i;
        uint32_t kv[8];
        #pragma unroll
        for (int j = 0; j < 8; ++j) {
            int idx = i + ((j < nb) ? j : 0);
            kv[j] = *reinterpret_cast<const uint32_t*>(
                        qkvs2 + (size_t)ssrc[idx] * 256 + 64 + 2 * lane);
        }
        #pragma unroll
        for (int j = 0; j < 8; ++j) {
            if (j < nb) {
                float p = q * b2f((uint16_t)kv[j]);
                p += __shfl_xor(p, 1);
                p += __shfl_xor(p, 2);
                p += __shfl_xor(p, 4);
                p += __shfl_xor(p, 8);
                p += __shfl_xor(p, 16);
                p += __shfl_xor(p, 32);
                float a = __expf(p * 0.125f);                 // 1/sqrt(64)
                den += a;
                acc = fmaf(a, b2f((uint16_t)(kv[j] >> 16)), acc);
            }
        }
    }

    float inv = (end > beg) ? 1.f / den : 0.f;
    out[(size_t)node * 64 + lane] = fmaf(acc, inv, b2f(base[192 + lane]));
}

extern "C" void kernel_launch(void* const* d_in, const int* in_sizes, int n_in,
                              void* d_out, int out_size, void* d_ws, size_t ws_size,
                              hipStream_t stream)
{
    const int N = in_sizes[0] / 128;
    const int E = in_sizes[1] / 2;

    const float* x   = (const float*)d_in[0];
    const int*   ei  = (const int*)d_in[1];
    const float* W1q = (const float*)d_in[2],  *b1q = (const float*)d_in[3];
    const float* W1k = (const float*)d_in[4],  *b1k = (const float*)d_in[5];
    const float* W1v = (const float*)d_in[6],  *b1v = (const float*)d_in[7];
    const float* W1s = (const float*)d_in[8],  *b1s = (const float*)d_in[9];
    const float* W2q = (const float*)d_in[10], *b2q = (const float*)d_in[11];
    const float* W2k = (const float*)d_in[12], *b2k = (const float*)d_in[13];
    const float* W2v = (const float*)d_in[14], *b2v = (const float*)d_in[15];
    const float* W2s = (const float*)d_in[16], *b2s = (const float*)d_in[17];

    char* ws = (char*)d_ws;
    size_t off = 0;
    auto alloc = [&](size_t bytes) { size_t r = off; off += (bytes + 255) & ~(size_t)255; return r; };

    uint16_t* qkvs1    = (uint16_t*)(ws + alloc((size_t)N * 512 * 2)); // 51.2 MB
    uint16_t* qkvs2    = qkvs1;   // overlay: qkvs1 dead before gemm2 writes qkvs2
    uint16_t* h        = (uint16_t*)(ws + alloc((size_t)N * 128 * 2)); // 12.8 MB
    int*      ssrc     = (int*)   (ws + alloc((size_t)E * 4));         // 3.2 MB
    int*      cnt      = (int*)   (ws + alloc((size_t)N * 4));
    int*      row_start= (int*)   (ws + alloc((size_t)(N + 1) * 4));
    int*      cursor   = (int*)   (ws + alloc((size_t)N * 4));
    int*      bsums    = (int*)   (ws + alloc(1024 * 4));
    uint16_t* Wt1      = (uint16_t*)(ws + alloc((size_t)128 * 512 * 2));
    float*    bc1      = (float*)  (ws + alloc(512 * 4));
    uint16_t* Wt2      = (uint16_t*)(ws + alloc((size_t)128 * 256 * 2));
    float*    bc2      = (float*)  (ws + alloc(256 * 4));
    float*    outF     = (float*)d_out;

    const int nb = (N + 1023) / 1024;

    hipMemsetAsync(cnt, 0, (size_t)N * 4, stream);

    pack_weights<1><<<(128 * 512 + 512 + 255) / 256, 256, 0, stream>>>(
        W1q, b1q, W1k, b1k, W1v, b1v, W1s, b1s, Wt1, bc1, 128, 128);
    pack_weights<2><<<(128 * 256 + 256 + 255) / 256, 256, 0, stream>>>(
        W2q, b2q, W2k, b2k, W2v, b2v, W2s, b2s, Wt2, bc2, 128, 64);

    // counting sort by dst (src-only payload; reused by both layers)
    hist_kernel<<<(E + 255) / 256, 256, 0, stream>>>(ei, E, cnt);
    scan_block_sums<<<nb, 256, 0, stream>>>(cnt, N, bsums);
    scan_write<<<nb, 256, 0, stream>>>(cnt, N, bsums, row_start, cursor);
    scatter_kernel<<<(E + 255) / 256, 256, 0, stream>>>(ei, E, cursor, ssrc);

    // layer 1: qkvs1 = x @ W1 + b1 (bf16), then gather
    dim3 g1((N + 63) / 64, 2);
    gemm_mfma<false><<<g1, 256, 0, stream>>>(x, Wt1, bc1, qkvs1, N, 512);
    node_pass1<<<(N * 64 + 255) / 256, 256, 0, stream>>>(ssrc, row_start, qkvs1, h, N);

    // layer 2 (qkvs2 overlays qkvs1; qkvs1 dead after node_pass1)
    dim3 g2((N + 63) / 64, 1);
    gemm_mfma<true><<<g2, 256, 0, stream>>>(h, Wt2, bc2, qkvs2, N, 256);
    node_pass2<<<(N * 64 + 255) / 256, 256, 0, stream>>>(ssrc, row_start, qkvs2, outF, N);
}

// Round 5
// 275.034 us; speedup vs baseline: 4.0788x; 1.2106x over previous
//
#include <hip/hip_runtime.h>
#include <hip/hip_bf16.h>
#include <stdint.h>

// ---------------------------------------------------------------------------
// TransformerGNN: two TransformerConv layers (4 heads cat -> relu -> 1 head)
// N=50000 nodes, E=800000 edges, IN=128, HID*HEADS=128, OUT=64
// Round 5: f16 pipeline + v_dot2_f32_f16; node passes process 4 edges/wave
// (16 lanes per edge, same dst node) to amortize scalar VALU work.
// ---------------------------------------------------------------------------

typedef _Float16 half_t;
typedef __attribute__((ext_vector_type(2))) _Float16 half2_t;
typedef __attribute__((ext_vector_type(8))) _Float16 half8;
typedef __attribute__((ext_vector_type(4))) float floatx4;

__device__ __forceinline__ uint16_t f2h(float f) {
    union { half_t h; uint16_t u; } c; c.h = (half_t)f; return c.u;
}
__device__ __forceinline__ half2_t u2h2(uint32_t u) {
    union { uint32_t u; half2_t h; } c; c.u = u; return c.h;
}
__device__ __forceinline__ float dot2(half2_t a, half2_t b, float c) {
#if __has_builtin(__builtin_amdgcn_fdot2)
    return __builtin_amdgcn_fdot2(a, b, c, false);
#else
    return fmaf((float)a.x, (float)b.x, fmaf((float)a.y, (float)b.y, c));
#endif
}

// ---------------------------------------------------------------------------
// pack 4 weight matrices (fp32 [K][Cper]) into transposed concat f16
// Wt[Ntot][K] with k/v-interleaved column layout, plus fp32 bias bc[Ntot].
// LAYER 1 (Cper=128): q->c | k->128+4*(c/2)+(c&1) | v->130+4*(c/2)+(c&1) | s->384+c
// LAYER 2 (Cper=64) : q->c | k->64+4*(c/2)+(c&1)  | v->66+4*(c/2)+(c&1)  | s->192+c
// ---------------------------------------------------------------------------
template <int LAYER>
__global__ void pack_weights(const float* __restrict__ Wq, const float* __restrict__ bq,
                             const float* __restrict__ Wk, const float* __restrict__ bk,
                             const float* __restrict__ Wv, const float* __restrict__ bv,
                             const float* __restrict__ Ws, const float* __restrict__ bs,
                             uint16_t* __restrict__ Wt, float* __restrict__ bc,
                             int K, int Cper)
{
    int Ntot = 4 * Cper;
    int idx = blockIdx.x * 256 + threadIdx.x;
    int total = K * Ntot;

    auto mapcol = [&](int m, int c) -> int {
        if (LAYER == 1) {
            if (m == 0) return c;
            if (m == 1) return 128 + 4 * (c >> 1) + (c & 1);
            if (m == 2) return 130 + 4 * (c >> 1) + (c & 1);
            return 384 + c;
        } else {
            if (m == 0) return c;
            if (m == 1) return 64 + 4 * (c >> 1) + (c & 1);
            if (m == 2) return 66 + 4 * (c >> 1) + (c & 1);
            return 192 + c;
        }
    };

    if (idx < total) {
        int m = idx / (Cper * K);
        int rem = idx - m * (Cper * K);
        int c = rem / K, k = rem % K;
        const float* Wm = (m == 0) ? Wq : (m == 1) ? Wk : (m == 2) ? Wv : Ws;
        Wt[(size_t)mapcol(m, c) * K + k] = f2h(Wm[k * Cper + c]);
    } else if (idx < total + Ntot) {
        int i = idx - total;
        int m = i / Cper, c = i % Cper;
        const float* bm = (m == 0) ? bq : (m == 1) ? bk : (m == 2) ? bv : bs;
        bc[mapcol(m, c)] = bm[c];
    }
}

// ---------------------------------------------------------------------------
// MFMA GEMM (f16): Y[M][Ntot] (f16) = A[M][128] @ W[128][Ntot] + bias
// Wt[Ntot][128] f16. A fp32 (layer1, converted at stage) or f16 (layer2).
// Block: 256 thr / 4 waves; BM=64 (16 rows per wave), BN=256, K=128.
// LDS tiles XOR-swizzled (byte ^= (row&7)<<4) for conflict-free ds_read_b128.
// ---------------------------------------------------------------------------
template <bool AFP32>
__global__ __launch_bounds__(256) void gemm_mfma(
    const void* __restrict__ Aptr, const uint16_t* __restrict__ Wt,
    const float* __restrict__ bias, uint16_t* __restrict__ Y,
    int M, int Ntot)
{
    __shared__ __align__(16) char Ab[64 * 256];    // 64 rows x 128 f16 (256B/row)
    __shared__ __align__(16) char Bb[256 * 256];   // 256 Wt-rows x 128 f16

    const int tid = threadIdx.x;
    const int m0 = blockIdx.x * 64;
    const int n0 = blockIdx.y * 256;

    #pragma unroll
    for (int i = 0; i < 4; ++i) {
        int g = tid + i * 256;
        int r = g >> 4, c8 = g & 15;
        int gr = m0 + r;
        uint16_t tmp[8];
        if (gr < M) {
            if (AFP32) {
                const float* ap = (const float*)Aptr + (size_t)gr * 128 + c8 * 8;
                float4 v0 = *(const float4*)ap;
                float4 v1 = *(const float4*)(ap + 4);
                tmp[0] = f2h(v0.x); tmp[1] = f2h(v0.y); tmp[2] = f2h(v0.z); tmp[3] = f2h(v0.w);
                tmp[4] = f2h(v1.x); tmp[5] = f2h(v1.y); tmp[6] = f2h(v1.z); tmp[7] = f2h(v1.w);
            } else {
                *(uint4*)tmp = *(const uint4*)((const uint16_t*)Aptr + (size_t)gr * 128 + c8 * 8);
            }
        } else {
            #pragma unroll
            for (int j = 0; j < 8; ++j) tmp[j] = 0;
        }
        int off = r * 256 + ((c8 * 16) ^ ((r & 7) << 4));
        *(uint4*)(Ab + off) = *(uint4*)tmp;
    }
    #pragma unroll
    for (int i = 0; i < 16; ++i) {
        int g = tid + i * 256;
        int n = g >> 4, c8 = g & 15;
        uint4 v = *(const uint4*)(Wt + (size_t)(n0 + n) * 128 + c8 * 8);
        int off = n * 256 + ((c8 * 16) ^ ((n & 7) << 4));
        *(uint4*)(Bb + off) = v;
    }
    __syncthreads();

    const int wv = tid >> 6, lane = tid & 63;
    const int lrow = lane & 15, kc = lane >> 4;    // kc = k-chunk 0..3

    half8 aF[4];
    const int ar = wv * 16 + lrow;
    #pragma unroll
    for (int ks = 0; ks < 4; ++ks) {
        int off = ar * 256 + ((ks * 64 + kc * 16) ^ ((ar & 7) << 4));
        aF[ks] = *(const half8*)(Ab + off);
    }

    floatx4 acc[16];
    #pragma unroll
    for (int t = 0; t < 16; ++t) acc[t] = (floatx4){0.f, 0.f, 0.f, 0.f};

    #pragma unroll
    for (int t = 0; t < 16; ++t) {
        const int nr = t * 16 + lrow;
        #pragma unroll
        for (int ks = 0; ks < 4; ++ks) {
            int off = nr * 256 + ((ks * 64 + kc * 16) ^ ((nr & 7) << 4));
            half8 bF = *(const half8*)(Bb + off);
            acc[t] = __builtin_amdgcn_mfma_f32_16x16x32_f16(aF[ks], bF, acc[t], 0, 0, 0);
        }
    }

    const int orow = m0 + wv * 16 + kc * 4;
    #pragma unroll
    for (int t = 0; t < 16; ++t) {
        int col = n0 + t * 16 + lrow;
        float bs = bias[col];
        #pragma unroll
        for (int j = 0; j < 4; ++j) {
            int gr = orow + j;
            if (gr < M) Y[(size_t)gr * Ntot + col] = f2h(acc[t][j] + bs);
        }
    }
}

// ---------------------------------------------------------------------------
// Counting sort of edges by dst. cnt -> row_start (exclusive scan) -> scatter
// ---------------------------------------------------------------------------
__global__ __launch_bounds__(256) void hist_kernel(const int* __restrict__ ei, int E,
                                                   int* __restrict__ cnt)
{
    int i = blockIdx.x * 256 + threadIdx.x;
    if (i < E) atomicAdd(&cnt[ei[E + i]], 1);
}

__global__ __launch_bounds__(256) void scan_block_sums(const int* __restrict__ cnt, int N,
                                                       int* __restrict__ bsums)
{
    __shared__ int red[256];
    int b = blockIdx.x, t = threadIdx.x;
    int base = b * 1024;
    int s = 0;
    #pragma unroll
    for (int j = 0; j < 4; ++j) {
        int i = base + t * 4 + j;
        if (i < N) s += cnt[i];
    }
    red[t] = s; __syncthreads();
    for (int off = 128; off > 0; off >>= 1) {
        if (t < off) red[t] += red[t + off];
        __syncthreads();
    }
    if (t == 0) bsums[b] = red[0];
}

__global__ __launch_bounds__(256) void scan_write(const int* __restrict__ cnt, int N,
                                                  const int* __restrict__ bsums,
                                                  int* __restrict__ row_start,
                                                  int* __restrict__ cursor)
{
    __shared__ int tsum[256];
    __shared__ int lds2[256];
    int b = blockIdx.x, t = threadIdx.x;

    int part = 0;
    for (int i = t; i < b; i += 256) part += bsums[i];
    tsum[t] = part; __syncthreads();
    for (int off = 128; off > 0; off >>= 1) {
        if (t < off) tsum[t] += tsum[t + off];
        __syncthreads();
    }
    int boff = tsum[0];
    __syncthreads();

    int base = b * 1024;
    int c[4]; int s = 0;
    #pragma unroll
    for (int j = 0; j < 4; ++j) {
        int i = base + t * 4 + j;
        c[j] = (i < N) ? cnt[i] : 0;
        s += c[j];
    }
    lds2[t] = s; __syncthreads();
    for (int off = 1; off < 256; off <<= 1) {
        int v = (t >= off) ? lds2[t - off] : 0;
        __syncthreads();
        lds2[t] += v;
        __syncthreads();
    }
    int excl = lds2[t] - s + boff;
    #pragma unroll
    for (int j = 0; j < 4; ++j) {
        int i = base + t * 4 + j;
        if (i < N) {
            row_start[i] = excl;
            cursor[i] = excl;
            excl += c[j];
            if (i == N - 1) row_start[N] = excl;
        }
    }
}

__global__ __launch_bounds__(256) void scatter_kernel(const int* __restrict__ ei, int E,
                                                      int* __restrict__ cursor,
                                                      int* __restrict__ ssrc)
{
    int i = blockIdx.x * 256 + threadIdx.x;
    if (i < E) {
        int d = ei[E + i];
        int p = atomicAdd(&cursor[d], 1);
        ssrc[p] = ei[i];
    }
}

// ---------------------------------------------------------------------------
// Layer 1 gather pass: one wave per dst node, 4 edges/wave (16 lanes each).
// qkvs row of 512 f16: [q 0:128 | kv ilv 128:384 | s 384:512]
// lane r of group g handles channels 8r..8r+7; head = r>>2.
// ---------------------------------------------------------------------------
__global__ __launch_bounds__(256) void node_pass1(
    const int* __restrict__ ssrc, const int* __restrict__ row_start,
    const uint16_t* __restrict__ qkvs, uint16_t* __restrict__ h, int N)
{
    int node = (blockIdx.x * 256 + threadIdx.x) >> 6;
    if (node >= N) return;
    const int lane = threadIdx.x & 63;
    const int g = lane >> 4, r = lane & 15;

    const uint16_t* base = qkvs + (size_t)node * 512;
    uint4 qw = *reinterpret_cast<const uint4*>(base + 8 * r);
    half2_t q01 = u2h2(qw.x), q23 = u2h2(qw.y), q45 = u2h2(qw.z), q67 = u2h2(qw.w);

    int beg = row_start[node], end = row_start[node + 1];
    float acc[8] = {0.f, 0.f, 0.f, 0.f, 0.f, 0.f, 0.f, 0.f};
    float den = 0.f;

    for (int i = beg; i < end; i += 8) {
        uint4 kvA[2], kvB[2];
        float ok[2];
        #pragma unroll
        for (int s = 0; s < 2; ++s) {
            int e = i + 4 * s + g;
            ok[s] = (e < end) ? 1.f : 0.f;
            int idx = (e < end) ? e : beg;
            const uint16_t* sb = qkvs + (size_t)ssrc[idx] * 512 + 128 + 16 * r;
            kvA[s] = *reinterpret_cast<const uint4*>(sb);
            kvB[s] = *reinterpret_cast<const uint4*>(sb + 8);
        }
        #pragma unroll
        for (int s = 0; s < 2; ++s) {
            float p = dot2(u2h2(kvA[s].x), q01, 0.f);
            p = dot2(u2h2(kvA[s].z), q23, p);
            p = dot2(u2h2(kvB[s].x), q45, p);
            p = dot2(u2h2(kvB[s].z), q67, p);
            p += __shfl_xor(p, 1);           // head = 4 lanes (32 ch)
            p += __shfl_xor(p, 2);
            float a = __expf(p * 0.17677669529663687f) * ok[s];  // 1/sqrt(32)
            den += a;
            half2_t v01 = u2h2(kvA[s].y), v23 = u2h2(kvA[s].w);
            half2_t v45 = u2h2(kvB[s].y), v67 = u2h2(kvB[s].w);
            acc[0] = fmaf((float)v01.x, a, acc[0]);
            acc[1] = fmaf((float)v01.y, a, acc[1]);
            acc[2] = fmaf((float)v23.x, a, acc[2]);
            acc[3] = fmaf((float)v23.y, a, acc[3]);
            acc[4] = fmaf((float)v45.x, a, acc[4]);
            acc[5] = fmaf((float)v45.y, a, acc[5]);
            acc[6] = fmaf((float)v67.x, a, acc[6]);
            acc[7] = fmaf((float)v67.y, a, acc[7]);
        }
    }

    // combine the 4 edge-groups (per-head den is lane-local: head(r)=r>>2)
    #pragma unroll
    for (int c = 0; c < 8; ++c) {
        acc[c] += __shfl_xor(acc[c], 16);
        acc[c] += __shfl_xor(acc[c], 32);
    }
    den += __shfl_xor(den, 16);
    den += __shfl_xor(den, 32);

    if (g == 0) {
        float inv = (end > beg) ? 1.f / den : 0.f;
        uint4 sw = *reinterpret_cast<const uint4*>(base + 384 + 8 * r);
        half2_t s01 = u2h2(sw.x), s23 = u2h2(sw.y), s45 = u2h2(sw.z), s67 = u2h2(sw.w);
        uint16_t o[8];
        o[0] = f2h(fmaxf(fmaf(acc[0], inv, (float)s01.x), 0.f));
        o[1] = f2h(fmaxf(fmaf(acc[1], inv, (float)s01.y), 0.f));
        o[2] = f2h(fmaxf(fmaf(acc[2], inv, (float)s23.x), 0.f));
        o[3] = f2h(fmaxf(fmaf(acc[3], inv, (float)s23.y), 0.f));
        o[4] = f2h(fmaxf(fmaf(acc[4], inv, (float)s45.x), 0.f));
        o[5] = f2h(fmaxf(fmaf(acc[5], inv, (float)s45.y), 0.f));
        o[6] = f2h(fmaxf(fmaf(acc[6], inv, (float)s67.x), 0.f));
        o[7] = f2h(fmaxf(fmaf(acc[7], inv, (float)s67.y), 0.f));
        *reinterpret_cast<uint4*>(h + (size_t)node * 128 + 8 * r) = *reinterpret_cast<uint4*>(o);
    }
}

// ---------------------------------------------------------------------------
// Layer 2 gather pass: one wave per dst node, 4 edges/wave (16 lanes each).
// qkvs2 row of 256 f16: [q 0:64 | kv ilv 64:192 | s 192:256]
// lane r handles channels 4r..4r+3 (1 head).
// ---------------------------------------------------------------------------
__global__ __launch_bounds__(256) void node_pass2(
    const int* __restrict__ ssrc, const int* __restrict__ row_start,
    const uint16_t* __restrict__ qkvs2, float* __restrict__ out, int N)
{
    int node = (blockIdx.x * 256 + threadIdx.x) >> 6;
    if (node >= N) return;
    const int lane = threadIdx.x & 63;
    const int g = lane >> 4, r = lane & 15;

    const uint16_t* base = qkvs2 + (size_t)node * 256;
    uint2 qw = *reinterpret_cast<const uint2*>(base + 4 * r);
    half2_t q01 = u2h2(qw.x), q23 = u2h2(qw.y);

    int beg = row_start[node], end = row_start[node + 1];
    float acc[4] = {0.f, 0.f, 0.f, 0.f};
    float den = 0.f;

    for (int i = beg; i < end; i += 8) {
        uint4 kv[2];
        float ok[2];
        #pragma unroll
        for (int s = 0; s < 2; ++s) {
            int e = i + 4 * s + g;
            ok[s] = (e < end) ? 1.f : 0.f;
            int idx = (e < end) ? e : beg;
            kv[s] = *reinterpret_cast<const uint4*>(
                        qkvs2 + (size_t)ssrc[idx] * 256 + 64 + 8 * r);
        }
        #pragma unroll
        for (int s = 0; s < 2; ++s) {
            float p = dot2(u2h2(kv[s].x), q01, 0.f);
            p = dot2(u2h2(kv[s].z), q23, p);
            p += __shfl_xor(p, 1);
            p += __shfl_xor(p, 2);
            p += __shfl_xor(p, 4);
            p += __shfl_xor(p, 8);
            float a = __expf(p * 0.125f) * ok[s];   // 1/sqrt(64)
            den += a;
            half2_t v01 = u2h2(kv[s].y), v23 = u2h2(kv[s].w);
            acc[0] = fmaf((float)v01.x, a, acc[0]);
            acc[1] = fmaf((float)v01.y, a, acc[1]);
            acc[2] = fmaf((float)v23.x, a, acc[2]);
            acc[3] = fmaf((float)v23.y, a, acc[3]);
        }
    }

    #pragma unroll
    for (int c = 0; c < 4; ++c) {
        acc[c] += __shfl_xor(acc[c], 16);
        acc[c] += __shfl_xor(acc[c], 32);
    }
    den += __shfl_xor(den, 16);
    den += __shfl_xor(den, 32);

    if (g == 0) {
        float inv = (end > beg) ? 1.f / den : 0.f;
        uint2 sw = *reinterpret_cast<const uint2*>(base + 192 + 4 * r);
        half2_t s01 = u2h2(sw.x), s23 = u2h2(sw.y);
        float4 o;
        o.x = fmaf(acc[0], inv, (float)s01.x);
        o.y = fmaf(acc[1], inv, (float)s01.y);
        o.z = fmaf(acc[2], inv, (float)s23.x);
        o.w = fmaf(acc[3], inv, (float)s23.y);
        *reinterpret_cast<float4*>(out + (size_t)node * 64 + 4 * r) = o;
    }
}

extern "C" void kernel_launch(void* const* d_in, const int* in_sizes, int n_in,
                              void* d_out, int out_size, void* d_ws, size_t ws_size,
                              hipStream_t stream)
{
    const int N = in_sizes[0] / 128;
    const int E = in_sizes[1] / 2;

    const float* x   = (const float*)d_in[0];
    const int*   ei  = (const int*)d_in[1];
    const float* W1q = (const float*)d_in[2],  *b1q = (const float*)d_in[3];
    const float* W1k = (const float*)d_in[4],  *b1k = (const float*)d_in[5];
    const float* W1v = (const float*)d_in[6],  *b1v = (const float*)d_in[7];
    const float* W1s = (const float*)d_in[8],  *b1s = (const float*)d_in[9];
    const float* W2q = (const float*)d_in[10], *b2q = (const float*)d_in[11];
    const float* W2k = (const float*)d_in[12], *b2k = (const float*)d_in[13];
    const float* W2v = (const float*)d_in[14], *b2v = (const float*)d_in[15];
    const float* W2s = (const float*)d_in[16], *b2s = (const float*)d_in[17];

    char* ws = (char*)d_ws;
    size_t off = 0;
    auto alloc = [&](size_t bytes) { size_t r = off; off += (bytes + 255) & ~(size_t)255; return r; };

    uint16_t* qkvs1    = (uint16_t*)(ws + alloc((size_t)N * 512 * 2)); // 51.2 MB
    uint16_t* qkvs2    = qkvs1;   // overlay: qkvs1 dead before gemm2 writes qkvs2
    uint16_t* h        = (uint16_t*)(ws + alloc((size_t)N * 128 * 2)); // 12.8 MB
    int*      ssrc     = (int*)   (ws + alloc((size_t)E * 4));         // 3.2 MB
    int*      cnt      = (int*)   (ws + alloc((size_t)N * 4));
    int*      row_start= (int*)   (ws + alloc((size_t)(N + 1) * 4));
    int*      cursor   = (int*)   (ws + alloc((size_t)N * 4));
    int*      bsums    = (int*)   (ws + alloc(1024 * 4));
    uint16_t* Wt1      = (uint16_t*)(ws + alloc((size_t)128 * 512 * 2));
    float*    bc1      = (float*)  (ws + alloc(512 * 4));
    uint16_t* Wt2      = (uint16_t*)(ws + alloc((size_t)128 * 256 * 2));
    float*    bc2      = (float*)  (ws + alloc(256 * 4));
    float*    outF     = (float*)d_out;

    const int nb = (N + 1023) / 1024;

    hipMemsetAsync(cnt, 0, (size_t)N * 4, stream);

    pack_weights<1><<<(128 * 512 + 512 + 255) / 256, 256, 0, stream>>>(
        W1q, b1q, W1k, b1k, W1v, b1v, W1s, b1s, Wt1, bc1, 128, 128);
    pack_weights<2><<<(128 * 256 + 256 + 255) / 256, 256, 0, stream>>>(
        W2q, b2q, W2k, b2k, W2v, b2v, W2s, b2s, Wt2, bc2, 128, 64);

    // counting sort by dst (src-only payload; reused by both layers)
    hist_kernel<<<(E + 255) / 256, 256, 0, stream>>>(ei, E, cnt);
    scan_block_sums<<<nb, 256, 0, stream>>>(cnt, N, bsums);
    scan_write<<<nb, 256, 0, stream>>>(cnt, N, bsums, row_start, cursor);
    scatter_kernel<<<(E + 255) / 256, 256, 0, stream>>>(ei, E, cursor, ssrc);

    // layer 1: qkvs1 = x @ W1 + b1 (f16), then gather
    dim3 g1((N + 63) / 64, 2);
    gemm_mfma<true><<<g1, 256, 0, stream>>>(x, Wt1, bc1, qkvs1, N, 512);
    node_pass1<<<(N * 64 + 255) / 256, 256, 0, stream>>>(ssrc, row_start, qkvs1, h, N);

    // layer 2 (qkvs2 overlays qkvs1; qkvs1 dead after node_pass1)
    dim3 g2((N + 63) / 64, 1);
    gemm_mfma<false><<<g2, 256, 0, stream>>>(h, Wt2, bc2, qkvs2, N, 256);
    node_pass2<<<(N * 64 + 255) / 256, 256, 0, stream>>>(ssrc, row_start, qkvs2, outF, N);
}